// Round 14
// baseline (295.053 us; speedup 1.0000x reference)
//
#include <hip/hip_runtime.h>
#include <hip/hip_bf16.h>

#define NEDGE 800000
#define NNODE 50000
#define DF    64
#define HID   128
#define NTILE (NEDGE / 16)
#define BLK   1024
#define WPB   16

using short8 = __attribute__((ext_vector_type(8))) short;
using f32x4  = __attribute__((ext_vector_type(4))) float;
using i32x4  = __attribute__((ext_vector_type(4))) int;

union P8 { unsigned int u[4]; short8 s; };

__device__ __forceinline__ unsigned int pk2(float lo, float hi) {
    union { __hip_bfloat162 p; unsigned int u; } c;
    c.p = __float22bfloat162_rn(float2{lo, hi});
    return c.u;
}

__device__ __forceinline__ short8 cvt8(f32x4 u, f32x4 v) {
    P8 p;
    p.u[0] = pk2(u[0], u[1]);
    p.u[1] = pk2(u[2], u[3]);
    p.u[2] = pk2(v[0], v[1]);
    p.u[3] = pk2(v[2], v[3]);
    return p.s;
}

__device__ __forceinline__ unsigned short bf1(float f) {
    union { __hip_bfloat16 b; unsigned short u; } c;
    c.b = __float2bfloat16(f);
    return c.u;
}

__device__ __forceinline__ float bf2f(unsigned short u) {
    union { unsigned int i; float f; } c;
    c.i = ((unsigned int)u) << 16;
    return c.f;
}

// HW transcendentals (R12: __expf/__fdividef are multi-op software without -ffast-math)
__device__ __forceinline__ float exp2_hw(float x) {
    float r; asm("v_exp_f32 %0, %1" : "=v"(r) : "v"(x)); return r;
}
__device__ __forceinline__ float rcp_hw(float x) {
    float r; asm("v_rcp_f32 %0, %1" : "=v"(r) : "v"(x)); return r;
}
__device__ __forceinline__ float silu_f(float v) {
    return v * rcp_hw(1.0f + exp2_hw(v * -1.44269504f));
}

// XOR-swizzled byte offset inside a row-major [R][128]-bf16 tile (row stride 256B).
__device__ __forceinline__ int swz(int r, int k) {
    return (r << 8) + ((((k >> 3) ^ (r & 7)) << 4) | ((k & 7) << 1));
}
__device__ __forceinline__ int swz16(int r, int slot) {
    return (r << 8) + ((slot ^ (r & 7)) << 4);
}

// ============== x f32 -> bf16 pre-convert (once; not per-edge) ==================
__global__ void __launch_bounds__(256)
stagex_kernel(const float* __restrict__ x, unsigned short* __restrict__ xb) {
    const int i = blockIdx.x * 256 + threadIdx.x;   // over 400000 groups of 8
    if (i < NNODE * DF / 8) {
        const f32x4 u = *(const f32x4*)(x + (size_t)i * 8);
        const f32x4 v = *(const f32x4*)(x + (size_t)i * 8 + 4);
        P8 p;
        p.u[0] = pk2(u[0], u[1]); p.u[1] = pk2(u[2], u[3]);
        p.u[2] = pk2(v[0], v[1]); p.u[3] = pk2(v[2], v[3]);
        *(short8*)(xb + (size_t)i * 8) = p.s;
    }
}

// ===================== CSR offsets: hist + 3-kernel scan ========================
__global__ void __launch_bounds__(256) hist_kernel(const int* __restrict__ ei,
                                                   int* __restrict__ counts) {
    const int i = blockIdx.x * 256 + threadIdx.x;
    if (i < 2 * NEDGE) atomicAdd(&counts[ei[i]], 1);
}

__global__ void __launch_bounds__(1024) scan1_kernel(const int* __restrict__ counts,
                                                     int* __restrict__ offs,
                                                     int* __restrict__ bsum) {
    __shared__ int buf[1024];
    const int tid = threadIdx.x;
    const int gid = blockIdx.x * 1024 + tid;
    const int v = (gid < NNODE) ? counts[gid] : 0;
    buf[tid] = v;
    __syncthreads();
#pragma unroll
    for (int off = 1; off < 1024; off <<= 1) {
        const int u = (tid >= off) ? buf[tid - off] : 0;
        __syncthreads();
        buf[tid] += u;
        __syncthreads();
    }
    if (gid < NNODE) offs[gid] = buf[tid] - v;     // block-local exclusive
    if (tid == 1023) bsum[blockIdx.x] = buf[1023];
}

__global__ void __launch_bounds__(1024) scan2_kernel(int* __restrict__ bsum, int nb) {
    __shared__ int buf[1024];
    const int tid = threadIdx.x;
    const int v = (tid < nb) ? bsum[tid] : 0;
    buf[tid] = v;
    __syncthreads();
#pragma unroll
    for (int off = 1; off < 1024; off <<= 1) {
        const int u = (tid >= off) ? buf[tid - off] : 0;
        __syncthreads();
        buf[tid] += u;
        __syncthreads();
    }
    if (tid < nb) bsum[tid] = buf[tid] - v;
}

__global__ void __launch_bounds__(1024) scan3_kernel(int* __restrict__ offs,
                                                     const int* __restrict__ bsum,
                                                     int* __restrict__ cursor) {
    const int gid = blockIdx.x * 1024 + threadIdx.x;
    if (gid < NNODE) {
        const int o = offs[gid] + bsum[blockIdx.x];
        offs[gid] = o;
        cursor[gid] = o;
    }
    if (gid == 0) offs[NNODE] = 2 * NEDGE;
}

// ====== Pass 1: edge MLP -> bf16 rows scattered DIRECTLY into CSR slots =========
// 1024-thread blocks (16 waves), 128KB LDS -> 1 block/CU = 4 waves/SIMD.
// x pre-staged as bf16: A-fragments are direct 16B loads (no per-edge cvt).
__global__ void __launch_bounds__(BLK, 4)
gnn_mlp_scatter(const unsigned short* __restrict__ xb, const int* __restrict__ ei,
                const float* __restrict__ t,
                const float* __restrict__ W1, const float* __restrict__ b1,
                const float* __restrict__ Wt, const float* __restrict__ bt,
                const float* __restrict__ W2, const float* __restrict__ b2,
                unsigned short* __restrict__ eout, int* __restrict__ cursor)
{
    extern __shared__ char lds[];
    char* const w1s = lds;            // 32KB: W1^T bf16, swizzled, PERMUTED rows
    char* const w2s = lds + 32768;    // 32KB: W2^T bf16, swizzled, PERMUTED rows
    const int tid  = threadIdx.x;
    const int wave = tid >> 6;
    const int lane = tid & 63;
    char* const hs = lds + 65536 + (wave << 12);

    // BOTH weights permuted: row rho=((j&7)<<4)+(j>>3) so step nt at lane jl
    // owns actual col jl*8+nt -> 8 ADJACENT cols (16B packed stores, both GEMMs).
    for (int idx = tid; idx < HID * HID; idx += BLK) {
        const int k = idx >> 7, j = idx & 127;
        const int rho = ((j & 7) << 4) + (j >> 3);
        *(unsigned short*)(w1s + swz(rho, k)) = bf1(W1[idx]);
        *(unsigned short*)(w2s + swz(rho, k)) = bf1(W2[idx]);
    }

    const int jl   = lane & 15;
    const int quad = lane >> 4;
    const int k0   = quad << 3;
    float wtj[8], btj[8], b1j[8], b2j[8];
#pragma unroll
    for (int nt = 0; nt < 8; nt++) {
        const int j = jl * 8 + nt;           // permuted col owned at step nt
        wtj[nt] = Wt[j]; btj[nt] = bt[j]; b1j[nt] = b1[j]; b2j[nt] = b2[j];
    }
    __syncthreads();

    const int gwave = blockIdx.x * WPB + wave;
    const int nwave = gridDim.x * WPB;

#define ISSUE_EI(T, RA, CA) { const int e_ = (T) * 16 + jl; RA = ei[e_]; CA = ei[NEDGE + e_]; }
#define ISSUE_X(RA, CA, X_) { \
    const unsigned short* xr_ = xb + (RA) * DF + k0; \
    const unsigned short* xc_ = xb + (CA) * DF + k0; \
    X_[0] = *(const short8*)(xr_);      X_[1] = *(const short8*)(xr_ + 32); \
    X_[2] = *(const short8*)(xc_);      X_[3] = *(const short8*)(xc_ + 32); }
#define ISSUE_EP(T, T4_, RI_, CI_) { const int er_ = (T) * 16 + (quad << 2); \
    T4_ = *(const f32x4*)(t + er_); \
    RI_ = *(const i32x4*)(ei + er_); \
    CI_ = *(const i32x4*)(ei + NEDGE + er_); }

    int tile = gwave;
    if (tile < NTILE) {
        int riA, ciA;  ISSUE_EI(tile, riA, ciA);
        short8 X[4];   ISSUE_X(riA, ciA, X);
        f32x4 T4; i32x4 RI, CI; ISSUE_EP(tile, T4, RI, CI);
        int tn  = tile + nwave;
        int tns = (tn < NTILE) ? tn : gwave;
        int riA_n, ciA_n; ISSUE_EI(tns, riA_n, ciA_n);

        while (tile < NTILE) {
            short8 Xn[4]; ISSUE_X(riA_n, ciA_n, Xn);
            f32x4 T4n; i32x4 RIn, CIn; ISSUE_EP(tns, T4n, RIn, CIn);
            const int t2  = tn + nwave;
            const int t2s = (t2 < NTILE) ? t2 : gwave;
            int riA_nn, ciA_nn; ISSUE_EI(t2s, riA_nn, ciA_nn);

            // ---- claim CSR slots: 2 fast u32 atomics per edge, broadcast via shfl
            int posS[4], posT[4];
            {
                unsigned int ps[4], pt[4];
#pragma unroll
                for (int r = 0; r < 4; r++) {
                    ps[r] = (jl == 0) ? atomicAdd((unsigned int*)&cursor[RI[r]], 1u) : 0u;
                    pt[r] = (jl == 8) ? atomicAdd((unsigned int*)&cursor[CI[r]], 1u) : 0u;
                }
#pragma unroll
                for (int r = 0; r < 4; r++) {
                    posS[r] = __shfl((int)ps[r], lane & 48);
                    posT[r] = __shfl((int)pt[r], (lane & 48) | 8);
                }
            }

            // ---- GEMM1 (permuted cols): A-frags are the raw bf16 loads
            f32x4 acc1[8];
#pragma unroll
            for (int nt = 0; nt < 8; nt++) {
                f32x4 acc = {0.f, 0.f, 0.f, 0.f};
                const int rho = nt * 16 + jl;
#pragma unroll
                for (int kk = 0; kk < 4; kk++) {
                    const short8 bfr = *(const short8*)(w1s + swz16(rho, (kk << 2) + quad));
                    acc = __builtin_amdgcn_mfma_f32_16x16x32_bf16(X[kk], bfr, acc, 0, 0, 0);
                }
                acc1[nt] = acc;
            }

            // h = silu(acc + silu(t*Wt+bt) + b1); 8 adjacent cols -> ONE b128 store/row
#pragma unroll
            for (int r = 0; r < 4; r++) {
                float h[8];
#pragma unroll
                for (int nt = 0; nt < 8; nt++) {
                    const float temb = silu_f(fmaf(T4[r], wtj[nt], btj[nt]));
                    h[nt] = silu_f(acc1[nt][r] + temb + b1j[nt]);
                }
                P8 p;
                p.u[0] = pk2(h[0], h[1]);
                p.u[1] = pk2(h[2], h[3]);
                p.u[2] = pk2(h[4], h[5]);
                p.u[3] = pk2(h[6], h[7]);
                *(short8*)(hs + swz16((quad << 2) + r, jl)) = p.s;
            }

            short8 a2[4];
#pragma unroll
            for (int kk = 0; kk < 4; kk++) {
                a2[kk] = *(const short8*)(hs + swz16(jl, (kk << 2) + quad));
            }

            // ---- GEMM2 (permuted cols: lane jl owns cols jl*8 .. jl*8+7)
            f32x4 acc2[8];
#pragma unroll
            for (int nt = 0; nt < 8; nt++) {
                f32x4 acc = {0.f, 0.f, 0.f, 0.f};
                const int rho = nt * 16 + jl;
#pragma unroll
                for (int kk = 0; kk < 4; kk++) {
                    const short8 bfr = *(const short8*)(w2s + swz16(rho, (kk << 2) + quad));
                    acc = __builtin_amdgcn_mfma_f32_16x16x32_bf16(a2[kk], bfr, acc, 0, 0, 0);
                }
                acc2[nt] = acc;
            }

            // ---- scatter rows into CSR slots: 128B contiguous (8 lanes x 16B)
#pragma unroll
            for (int r = 0; r < 4; r++) {
                const int pos = (jl < 8) ? posS[r] : posT[r];
                unsigned short* dst = eout + (size_t)pos * 64 + ((jl & 7) << 3);
                P8 p;
                p.u[0] = pk2(acc2[0][r] + b2j[0], acc2[1][r] + b2j[1]);
                p.u[1] = pk2(acc2[2][r] + b2j[2], acc2[3][r] + b2j[3]);
                p.u[2] = pk2(acc2[4][r] + b2j[4], acc2[5][r] + b2j[5]);
                p.u[3] = pk2(acc2[6][r] + b2j[6], acc2[7][r] + b2j[7]);
                *(short8*)dst = p.s;
            }

            // ---- rotate pipeline state
            tile = tn; tn = t2; tns = t2s;
#pragma unroll
            for (int i = 0; i < 4; i++) X[i] = Xn[i];
            T4 = T4n; RI = RIn; CI = CIn;
            riA_n = riA_nn; ciA_n = ciA_nn;
        }
    }
#undef ISSUE_EI
#undef ISSUE_X
#undef ISSUE_EP
}

// ======= Pass 2: per-node gather; 16B/lane loads, 8 rows (1KB) per iter =========
__global__ void __launch_bounds__(256)
gather_kernel(const unsigned short* __restrict__ eout, const int* __restrict__ offs,
              float* __restrict__ out)
{
    const int wave = threadIdx.x >> 6;
    const int lane = threadIdx.x & 63;
    const int n = blockIdx.x * 4 + wave;
    if (n >= NNODE) return;
    const int o0 = offs[n], o1 = offs[n + 1];

    const int cg = lane & 7;     // column group (8 bf16 = 16B)
    const int rp = lane >> 3;    // row phase 0..7
    float acc[8] = {0.f, 0.f, 0.f, 0.f, 0.f, 0.f, 0.f, 0.f};
    for (int k = o0 + rp; k < o1; k += 8) {
        const short8 v = *(const short8*)(eout + (size_t)k * 64 + (cg << 3));
#pragma unroll
        for (int j = 0; j < 8; j++) acc[j] += bf2f((unsigned short)v[j]);
    }
#pragma unroll
    for (int j = 0; j < 8; j++) {
        acc[j] += __shfl_xor(acc[j], 8);
        acc[j] += __shfl_xor(acc[j], 16);
        acc[j] += __shfl_xor(acc[j], 32);
    }
    if (rp == 0) {
        float* o = out + (size_t)n * DF + (cg << 3);
        *(f32x4*)(o)     = f32x4{acc[0], acc[1], acc[2], acc[3]};
        *(f32x4*)(o + 4) = f32x4{acc[4], acc[5], acc[6], acc[7]};
    }
}

// ==================== Fallback: fused atomic version (R3, proven 372us) =========
__global__ void __launch_bounds__(256, 2)
gnn_fused_atomic(const float* __restrict__ x, const int* __restrict__ ei,
                 const float* __restrict__ t,
                 const float* __restrict__ W1, const float* __restrict__ b1,
                 const float* __restrict__ Wt, const float* __restrict__ bt,
                 const float* __restrict__ W2, const float* __restrict__ b2,
                 float* __restrict__ out)
{
    extern __shared__ char lds[];
    char* const w1s = lds;
    char* const w2s = lds + 32768;
    const int tid  = threadIdx.x;
    const int wave = tid >> 6;
    const int lane = tid & 63;
    char* const hs = lds + 65536 + (wave << 12);

    for (int idx = tid; idx < HID * HID; idx += 256) {
        const int k = idx >> 7, j = idx & 127;
        const int off = swz(j, k);
        *(unsigned short*)(w1s + off) = bf1(W1[idx]);
        *(unsigned short*)(w2s + off) = bf1(W2[idx]);
    }

    const int jl   = lane & 15;
    const int quad = lane >> 4;
    const int k0   = quad << 3;
    float wtj[8], btj[8], b1j[8], b2j[8];
#pragma unroll
    for (int nt = 0; nt < 8; nt++) {
        const int j = nt * 16 + jl;
        wtj[nt] = Wt[j]; btj[nt] = bt[j]; b1j[nt] = b1[j]; b2j[nt] = b2[j];
    }
    __syncthreads();

    const int gwave = (blockIdx.x << 2) + wave;
    const int nwave = gridDim.x << 2;

    for (int tile = gwave; tile < NTILE; tile += nwave) {
        const int base = tile << 4;
        const int eA = base + jl;
        const int ri = ei[eA];
        const int ci = ei[NEDGE + eA];

        short8 a[4];
        {
            const float* xr_ = x + ri * DF + k0;
            const float* xc_ = x + ci * DF + k0;
            a[0] = cvt8(*(const f32x4*)(xr_),      *(const f32x4*)(xr_ + 4));
            a[1] = cvt8(*(const f32x4*)(xr_ + 32), *(const f32x4*)(xr_ + 36));
            a[2] = cvt8(*(const f32x4*)(xc_),      *(const f32x4*)(xc_ + 4));
            a[3] = cvt8(*(const f32x4*)(xc_ + 32), *(const f32x4*)(xc_ + 36));
        }

        const int er = base + (quad << 2);
        const f32x4 T4 = *(const f32x4*)(t + er);
        const i32x4 RI = *(const i32x4*)(ei + er);
        const i32x4 CI = *(const i32x4*)(ei + NEDGE + er);

#pragma unroll
        for (int nt = 0; nt < 8; nt++) {
            f32x4 acc = {0.f, 0.f, 0.f, 0.f};
            const int j = nt * 16 + jl;
#pragma unroll
            for (int kk = 0; kk < 4; kk++) {
                const short8 bfr = *(const short8*)(w1s + swz16(j, (kk << 2) + quad));
                acc = __builtin_amdgcn_mfma_f32_16x16x32_bf16(a[kk], bfr, acc, 0, 0, 0);
            }
#pragma unroll
            for (int r = 0; r < 4; r++) {
                const float temb = silu_f(fmaf(T4[r], wtj[nt], btj[nt]));
                const float h = silu_f(acc[r] + temb + b1j[nt]);
                *(unsigned short*)(hs + swz((quad << 2) + r, j)) = bf1(h);
            }
        }

        short8 a2[4];
#pragma unroll
        for (int kk = 0; kk < 4; kk++) {
            a2[kk] = *(const short8*)(hs + swz16(jl, (kk << 2) + quad));
        }

#pragma unroll
        for (int nt = 0; nt < 8; nt++) {
            f32x4 acc = {0.f, 0.f, 0.f, 0.f};
            const int j = nt * 16 + jl;
#pragma unroll
            for (int kk = 0; kk < 4; kk++) {
                const short8 bfr = *(const short8*)(w2s + swz16(j, (kk << 2) + quad));
                acc = __builtin_amdgcn_mfma_f32_16x16x32_bf16(a2[kk], bfr, acc, 0, 0, 0);
            }
#pragma unroll
            for (int r = 0; r < 4; r++) {
                const float v = acc[r] + b2j[nt];
                const int node = (nt < 4) ? RI[r] : CI[r];
                unsafeAtomicAdd(out + node * DF + (j & 63), v);
            }
        }
    }
}

extern "C" void kernel_launch(void* const* d_in, const int* in_sizes, int n_in,
                              void* d_out, int out_size, void* d_ws, size_t ws_size,
                              hipStream_t stream) {
    const float* x  = (const float*)d_in[0];
    const int*   ei = (const int*)d_in[1];
    const float* t  = (const float*)d_in[2];
    const float* W1 = (const float*)d_in[3];
    const float* b1 = (const float*)d_in[4];
    const float* Wt = (const float*)d_in[5];
    const float* bt = (const float*)d_in[6];
    const float* W2 = (const float*)d_in[7];
    const float* b2 = (const float*)d_in[8];
    float* out = (float*)d_out;

    const size_t eoutB = (size_t)(2 * NEDGE) * 64 * sizeof(unsigned short);  // 204.8 MB
    const size_t need  = eoutB + (size_t)(3 * NNODE + 1 + 1024) * sizeof(int) + 256;

    if (ws_size >= need) {
        char* wsb = (char*)d_ws;
        unsigned short* eout = (unsigned short*)wsb;
        int* counts = (int*)(wsb + eoutB);
        int* offs   = counts + NNODE;          // NNODE+1
        int* bsum   = offs + NNODE + 1;        // 1024
        int* cursor = bsum + 1024;             // NNODE

        // x-bf16 staged in d_out (6.4MB of 12.8MB); dead before gather overwrites out.
        unsigned short* xb = (unsigned short*)d_out;

        const int nsb = (NNODE + 1023) / 1024;  // 49

        hipLaunchKernelGGL(stagex_kernel, dim3((NNODE * DF / 8 + 255) / 256), dim3(256),
                           0, stream, x, xb);
        (void)hipMemsetAsync(counts, 0, (size_t)NNODE * sizeof(int), stream);
        hipLaunchKernelGGL(hist_kernel, dim3((2 * NEDGE + 255) / 256), dim3(256), 0, stream,
                           ei, counts);
        hipLaunchKernelGGL(scan1_kernel, dim3(nsb), dim3(1024), 0, stream,
                           counts, offs, bsum);
        hipLaunchKernelGGL(scan2_kernel, dim3(1), dim3(1024), 0, stream, bsum, nsb);
        hipLaunchKernelGGL(scan3_kernel, dim3(nsb), dim3(1024), 0, stream,
                           offs, bsum, cursor);

        const int ldsMlp = 65536 + WPB * 4096;  // 128KB -> 1 block (16 waves)/CU
        (void)hipFuncSetAttribute((const void*)gnn_mlp_scatter,
                                  hipFuncAttributeMaxDynamicSharedMemorySize, ldsMlp);
        hipLaunchKernelGGL(gnn_mlp_scatter, dim3(256), dim3(BLK), ldsMlp, stream,
                           xb, ei, t, W1, b1, Wt, bt, W2, b2, eout, cursor);

        hipLaunchKernelGGL(gather_kernel, dim3((NNODE + 3) / 4), dim3(256), 0, stream,
                           eout, offs, out);
    } else {
        // fallback: fused atomic version (proven, ~372us)
        const int ldsBytes = 65536 + 4 * 4096;
        (void)hipMemsetAsync(out, 0, (size_t)out_size * sizeof(float), stream);
        (void)hipFuncSetAttribute((const void*)gnn_fused_atomic,
                                  hipFuncAttributeMaxDynamicSharedMemorySize, ldsBytes);
        hipLaunchKernelGGL(gnn_fused_atomic, dim3(512), dim3(256), ldsBytes, stream,
                           x, ei, t, W1, b1, Wt, bt, W2, b2, out);
    }
}

// Round 15
// 240.776 us; speedup vs baseline: 1.2254x; 1.2254x over previous
//
#include <hip/hip_runtime.h>
#include <hip/hip_bf16.h>

#define NEDGE 800000
#define NNODE 50000
#define DF    64
#define HID   128
#define NTILE (NEDGE / 16)
#define BLK   768
#define WPB   12

using short8 = __attribute__((ext_vector_type(8))) short;
using f32x4  = __attribute__((ext_vector_type(4))) float;
using i32x4  = __attribute__((ext_vector_type(4))) int;

union P8 { unsigned int u[4]; short8 s; };

__device__ __forceinline__ unsigned int pk2(float lo, float hi) {
    union { __hip_bfloat162 p; unsigned int u; } c;
    c.p = __float22bfloat162_rn(float2{lo, hi});
    return c.u;
}

__device__ __forceinline__ unsigned short bf1(float f) {
    union { __hip_bfloat16 b; unsigned short u; } c;
    c.b = __float2bfloat16(f);
    return c.u;
}

__device__ __forceinline__ float bf2f(unsigned short u) {
    union { unsigned int i; float f; } c;
    c.i = ((unsigned int)u) << 16;
    return c.f;
}

// HW transcendentals (R12: __expf/__fdividef are multi-op software without -ffast-math)
__device__ __forceinline__ float exp2_hw(float x) {
    float r; asm("v_exp_f32 %0, %1" : "=v"(r) : "v"(x)); return r;
}
__device__ __forceinline__ float rcp_hw(float x) {
    float r; asm("v_rcp_f32 %0, %1" : "=v"(r) : "v"(x)); return r;
}
__device__ __forceinline__ float silu_f(float v) {
    return v * rcp_hw(1.0f + exp2_hw(v * -1.44269504f));
}

// XOR-swizzled byte offset inside a row-major [R][128]-bf16 tile (row stride 256B).
__device__ __forceinline__ int swz(int r, int k) {
    return (r << 8) + ((((k >> 3) ^ (r & 7)) << 4) | ((k & 7) << 1));
}
__device__ __forceinline__ int swz16(int r, int slot) {
    return (r << 8) + ((slot ^ (r & 7)) << 4);
}

// ============== x f32 -> bf16 pre-convert (once; not per-edge) ==================
__global__ void __launch_bounds__(256)
stagex_kernel(const float* __restrict__ x, unsigned short* __restrict__ xb) {
    const int i = blockIdx.x * 256 + threadIdx.x;   // over 400000 groups of 8
    if (i < NNODE * DF / 8) {
        const f32x4 u = *(const f32x4*)(x + (size_t)i * 8);
        const f32x4 v = *(const f32x4*)(x + (size_t)i * 8 + 4);
        P8 p;
        p.u[0] = pk2(u[0], u[1]); p.u[1] = pk2(u[2], u[3]);
        p.u[2] = pk2(v[0], v[1]); p.u[3] = pk2(v[2], v[3]);
        *(short8*)(xb + (size_t)i * 8) = p.s;
    }
}

// ===================== CSR offsets: hist + 3-kernel scan ========================
__global__ void __launch_bounds__(256) hist_kernel(const int* __restrict__ ei,
                                                   int* __restrict__ counts) {
    const int i = blockIdx.x * 256 + threadIdx.x;
    if (i < 2 * NEDGE) atomicAdd(&counts[ei[i]], 1);
}

__global__ void __launch_bounds__(1024) scan1_kernel(const int* __restrict__ counts,
                                                     int* __restrict__ offs,
                                                     int* __restrict__ bsum) {
    __shared__ int buf[1024];
    const int tid = threadIdx.x;
    const int gid = blockIdx.x * 1024 + tid;
    const int v = (gid < NNODE) ? counts[gid] : 0;
    buf[tid] = v;
    __syncthreads();
#pragma unroll
    for (int off = 1; off < 1024; off <<= 1) {
        const int u = (tid >= off) ? buf[tid - off] : 0;
        __syncthreads();
        buf[tid] += u;
        __syncthreads();
    }
    if (gid < NNODE) offs[gid] = buf[tid] - v;     // block-local exclusive
    if (tid == 1023) bsum[blockIdx.x] = buf[1023];
}

__global__ void __launch_bounds__(1024) scan2_kernel(int* __restrict__ bsum, int nb) {
    __shared__ int buf[1024];
    const int tid = threadIdx.x;
    const int v = (tid < nb) ? bsum[tid] : 0;
    buf[tid] = v;
    __syncthreads();
#pragma unroll
    for (int off = 1; off < 1024; off <<= 1) {
        const int u = (tid >= off) ? buf[tid - off] : 0;
        __syncthreads();
        buf[tid] += u;
        __syncthreads();
    }
    if (tid < nb) bsum[tid] = buf[tid] - v;
}

__global__ void __launch_bounds__(1024) scan3_kernel(int* __restrict__ offs,
                                                     const int* __restrict__ bsum,
                                                     int* __restrict__ cursor) {
    const int gid = blockIdx.x * 1024 + threadIdx.x;
    if (gid < NNODE) {
        const int o = offs[gid] + bsum[blockIdx.x];
        offs[gid] = o;
        cursor[gid] = o;
    }
    if (gid == 0) offs[NNODE] = 2 * NEDGE;
}

// ====== Pass 1: edge MLP -> bf16 rows scattered DIRECTLY into CSR slots =========
// 768 threads / 3 waves-per-SIMD (R13-proven: VGPR 84, no spill); xb pre-staged.
__global__ void __launch_bounds__(BLK, 3)
gnn_mlp_scatter(const unsigned short* __restrict__ xb, const int* __restrict__ ei,
                const float* __restrict__ t,
                const float* __restrict__ W1, const float* __restrict__ b1,
                const float* __restrict__ Wt, const float* __restrict__ bt,
                const float* __restrict__ W2, const float* __restrict__ b2,
                unsigned short* __restrict__ eout, int* __restrict__ cursor)
{
    extern __shared__ char lds[];
    char* const w1s = lds;            // 32KB: W1^T bf16, swizzled, PERMUTED rows
    char* const w2s = lds + 32768;    // 32KB: W2^T bf16, swizzled, PERMUTED rows
    const int tid  = threadIdx.x;
    const int wave = tid >> 6;
    const int lane = tid & 63;
    char* const hs = lds + 65536 + (wave << 12);

    // BOTH weights permuted: row rho=((j&7)<<4)+(j>>3) so step nt at lane jl
    // owns actual col jl*8+nt -> 8 ADJACENT cols (16B packed stores, both GEMMs).
    for (int idx = tid; idx < HID * HID; idx += BLK) {
        const int k = idx >> 7, j = idx & 127;
        const int rho = ((j & 7) << 4) + (j >> 3);
        *(unsigned short*)(w1s + swz(rho, k)) = bf1(W1[idx]);
        *(unsigned short*)(w2s + swz(rho, k)) = bf1(W2[idx]);
    }

    const int jl   = lane & 15;
    const int quad = lane >> 4;
    const int k0   = quad << 3;
    float wtj[8], btj[8], b1j[8], b2j[8];
#pragma unroll
    for (int nt = 0; nt < 8; nt++) {
        const int j = jl * 8 + nt;           // permuted col owned at step nt
        wtj[nt] = Wt[j]; btj[nt] = bt[j]; b1j[nt] = b1[j]; b2j[nt] = b2[j];
    }
    __syncthreads();

    const int gwave = blockIdx.x * WPB + wave;
    const int nwave = gridDim.x * WPB;

#define ISSUE_EI(T, RA, CA) { const int e_ = (T) * 16 + jl; RA = ei[e_]; CA = ei[NEDGE + e_]; }
#define ISSUE_X(RA, CA, X_) { \
    const unsigned short* xr_ = xb + (RA) * DF + k0; \
    const unsigned short* xc_ = xb + (CA) * DF + k0; \
    X_[0] = *(const short8*)(xr_);      X_[1] = *(const short8*)(xr_ + 32); \
    X_[2] = *(const short8*)(xc_);      X_[3] = *(const short8*)(xc_ + 32); }
#define ISSUE_EP(T, T4_, RI_, CI_) { const int er_ = (T) * 16 + (quad << 2); \
    T4_ = *(const f32x4*)(t + er_); \
    RI_ = *(const i32x4*)(ei + er_); \
    CI_ = *(const i32x4*)(ei + NEDGE + er_); }

    int tile = gwave;
    if (tile < NTILE) {
        int riA, ciA;  ISSUE_EI(tile, riA, ciA);
        short8 X[4];   ISSUE_X(riA, ciA, X);
        f32x4 T4; i32x4 RI, CI; ISSUE_EP(tile, T4, RI, CI);
        int tn  = tile + nwave;
        int tns = (tn < NTILE) ? tn : gwave;
        int riA_n, ciA_n; ISSUE_EI(tns, riA_n, ciA_n);

        while (tile < NTILE) {
            short8 Xn[4]; ISSUE_X(riA_n, ciA_n, Xn);
            f32x4 T4n; i32x4 RIn, CIn; ISSUE_EP(tns, T4n, RIn, CIn);
            const int t2  = tn + nwave;
            const int t2s = (t2 < NTILE) ? t2 : gwave;
            int riA_nn, ciA_nn; ISSUE_EI(t2s, riA_nn, ciA_nn);

            // ---- claim CSR slots: 2 fast u32 atomics per edge, broadcast via shfl
            int posS[4], posT[4];
            {
                unsigned int ps[4], pt[4];
#pragma unroll
                for (int r = 0; r < 4; r++) {
                    ps[r] = (jl == 0) ? atomicAdd((unsigned int*)&cursor[RI[r]], 1u) : 0u;
                    pt[r] = (jl == 8) ? atomicAdd((unsigned int*)&cursor[CI[r]], 1u) : 0u;
                }
#pragma unroll
                for (int r = 0; r < 4; r++) {
                    posS[r] = __shfl((int)ps[r], lane & 48);
                    posT[r] = __shfl((int)pt[r], (lane & 48) | 8);
                }
            }

            // ---- GEMM1 (permuted cols): A-frags are the raw bf16 loads
            f32x4 acc1[8];
#pragma unroll
            for (int nt = 0; nt < 8; nt++) {
                f32x4 acc = {0.f, 0.f, 0.f, 0.f};
                const int rho = nt * 16 + jl;
#pragma unroll
                for (int kk = 0; kk < 4; kk++) {
                    const short8 bfr = *(const short8*)(w1s + swz16(rho, (kk << 2) + quad));
                    acc = __builtin_amdgcn_mfma_f32_16x16x32_bf16(X[kk], bfr, acc, 0, 0, 0);
                }
                acc1[nt] = acc;
            }

            // h = silu(acc + silu(t*Wt+bt) + b1); 8 adjacent cols -> ONE b128 store/row
#pragma unroll
            for (int r = 0; r < 4; r++) {
                float h[8];
#pragma unroll
                for (int nt = 0; nt < 8; nt++) {
                    const float temb = silu_f(fmaf(T4[r], wtj[nt], btj[nt]));
                    h[nt] = silu_f(acc1[nt][r] + temb + b1j[nt]);
                }
                P8 p;
                p.u[0] = pk2(h[0], h[1]);
                p.u[1] = pk2(h[2], h[3]);
                p.u[2] = pk2(h[4], h[5]);
                p.u[3] = pk2(h[6], h[7]);
                *(short8*)(hs + swz16((quad << 2) + r, jl)) = p.s;
            }

            short8 a2[4];
#pragma unroll
            for (int kk = 0; kk < 4; kk++) {
                a2[kk] = *(const short8*)(hs + swz16(jl, (kk << 2) + quad));
            }

            // ---- GEMM2 (permuted cols: lane jl owns cols jl*8 .. jl*8+7)
            f32x4 acc2[8];
#pragma unroll
            for (int nt = 0; nt < 8; nt++) {
                f32x4 acc = {0.f, 0.f, 0.f, 0.f};
                const int rho = nt * 16 + jl;
#pragma unroll
                for (int kk = 0; kk < 4; kk++) {
                    const short8 bfr = *(const short8*)(w2s + swz16(rho, (kk << 2) + quad));
                    acc = __builtin_amdgcn_mfma_f32_16x16x32_bf16(a2[kk], bfr, acc, 0, 0, 0);
                }
                acc2[nt] = acc;
            }

            // ---- scatter rows into CSR slots: 128B contiguous (8 lanes x 16B)
#pragma unroll
            for (int r = 0; r < 4; r++) {
                const int pos = (jl < 8) ? posS[r] : posT[r];
                unsigned short* dst = eout + (size_t)pos * 64 + ((jl & 7) << 3);
                P8 p;
                p.u[0] = pk2(acc2[0][r] + b2j[0], acc2[1][r] + b2j[1]);
                p.u[1] = pk2(acc2[2][r] + b2j[2], acc2[3][r] + b2j[3]);
                p.u[2] = pk2(acc2[4][r] + b2j[4], acc2[5][r] + b2j[5]);
                p.u[3] = pk2(acc2[6][r] + b2j[6], acc2[7][r] + b2j[7]);
                *(short8*)dst = p.s;
            }

            // ---- rotate pipeline state
            tile = tn; tn = t2; tns = t2s;
#pragma unroll
            for (int i = 0; i < 4; i++) X[i] = Xn[i];
            T4 = T4n; RI = RIn; CI = CIn;
            riA_n = riA_nn; ciA_n = ciA_nn;
        }
    }
#undef ISSUE_EI
#undef ISSUE_X
#undef ISSUE_EP
}

// ======= Pass 2: per-node gather; 16B/lane loads, 8 rows (1KB) per iter =========
__global__ void __launch_bounds__(256)
gather_kernel(const unsigned short* __restrict__ eout, const int* __restrict__ offs,
              float* __restrict__ out)
{
    const int wave = threadIdx.x >> 6;
    const int lane = threadIdx.x & 63;
    const int n = blockIdx.x * 4 + wave;
    if (n >= NNODE) return;
    const int o0 = offs[n], o1 = offs[n + 1];

    const int cg = lane & 7;     // column group (8 bf16 = 16B)
    const int rp = lane >> 3;    // row phase 0..7
    float acc[8] = {0.f, 0.f, 0.f, 0.f, 0.f, 0.f, 0.f, 0.f};
    for (int k = o0 + rp; k < o1; k += 8) {
        const short8 v = *(const short8*)(eout + (size_t)k * 64 + (cg << 3));
#pragma unroll
        for (int j = 0; j < 8; j++) acc[j] += bf2f((unsigned short)v[j]);
    }
#pragma unroll
    for (int j = 0; j < 8; j++) {
        acc[j] += __shfl_xor(acc[j], 8);
        acc[j] += __shfl_xor(acc[j], 16);
        acc[j] += __shfl_xor(acc[j], 32);
    }
    if (rp == 0) {
        float* o = out + (size_t)n * DF + (cg << 3);
        *(f32x4*)(o)     = f32x4{acc[0], acc[1], acc[2], acc[3]};
        *(f32x4*)(o + 4) = f32x4{acc[4], acc[5], acc[6], acc[7]};
    }
}

// ==================== Fallback: fused atomic version (R3, proven 372us) =========
__global__ void __launch_bounds__(256, 2)
gnn_fused_atomic(const float* __restrict__ x, const int* __restrict__ ei,
                 const float* __restrict__ t,
                 const float* __restrict__ W1, const float* __restrict__ b1,
                 const float* __restrict__ Wt, const float* __restrict__ bt,
                 const float* __restrict__ W2, const float* __restrict__ b2,
                 float* __restrict__ out)
{
    extern __shared__ char lds[];
    char* const w1s = lds;
    char* const w2s = lds + 32768;
    const int tid  = threadIdx.x;
    const int wave = tid >> 6;
    const int lane = tid & 63;
    char* const hs = lds + 65536 + (wave << 12);

    for (int idx = tid; idx < HID * HID; idx += 256) {
        const int k = idx >> 7, j = idx & 127;
        const int off = swz(j, k);
        *(unsigned short*)(w1s + off) = bf1(W1[idx]);
        *(unsigned short*)(w2s + off) = bf1(W2[idx]);
    }

    const int jl   = lane & 15;
    const int quad = lane >> 4;
    const int k0   = quad << 3;
    float wtj[8], btj[8], b1j[8], b2j[8];
#pragma unroll
    for (int nt = 0; nt < 8; nt++) {
        const int j = nt * 16 + jl;
        wtj[nt] = Wt[j]; btj[nt] = bt[j]; b1j[nt] = b1[j]; b2j[nt] = b2[j];
    }
    __syncthreads();

    const int gwave = (blockIdx.x << 2) + wave;
    const int nwave = gridDim.x << 2;

    for (int tile = gwave; tile < NTILE; tile += nwave) {
        const int base = tile << 4;
        const int eA = base + jl;
        const int ri = ei[eA];
        const int ci = ei[NEDGE + eA];

        short8 a[4];
        {
            const float* xr_ = x + ri * DF + k0;
            const float* xc_ = x + ci * DF + k0;
            f32x4 u0 = *(const f32x4*)(xr_),      v0 = *(const f32x4*)(xr_ + 4);
            f32x4 u1 = *(const f32x4*)(xr_ + 32), v1 = *(const f32x4*)(xr_ + 36);
            f32x4 u2 = *(const f32x4*)(xc_),      v2 = *(const f32x4*)(xc_ + 4);
            f32x4 u3 = *(const f32x4*)(xc_ + 32), v3 = *(const f32x4*)(xc_ + 36);
            P8 p0, p1, p2, p3;
            p0.u[0]=pk2(u0[0],u0[1]); p0.u[1]=pk2(u0[2],u0[3]); p0.u[2]=pk2(v0[0],v0[1]); p0.u[3]=pk2(v0[2],v0[3]);
            p1.u[0]=pk2(u1[0],u1[1]); p1.u[1]=pk2(u1[2],u1[3]); p1.u[2]=pk2(v1[0],v1[1]); p1.u[3]=pk2(v1[2],v1[3]);
            p2.u[0]=pk2(u2[0],u2[1]); p2.u[1]=pk2(u2[2],u2[3]); p2.u[2]=pk2(v2[0],v2[1]); p2.u[3]=pk2(v2[2],v2[3]);
            p3.u[0]=pk2(u3[0],u3[1]); p3.u[1]=pk2(u3[2],u3[3]); p3.u[2]=pk2(v3[0],v3[1]); p3.u[3]=pk2(v3[2],v3[3]);
            a[0]=p0.s; a[1]=p1.s; a[2]=p2.s; a[3]=p3.s;
        }

        const int er = base + (quad << 2);
        const f32x4 T4 = *(const f32x4*)(t + er);
        const i32x4 RI = *(const i32x4*)(ei + er);
        const i32x4 CI = *(const i32x4*)(ei + NEDGE + er);

#pragma unroll
        for (int nt = 0; nt < 8; nt++) {
            f32x4 acc = {0.f, 0.f, 0.f, 0.f};
            const int j = nt * 16 + jl;
#pragma unroll
            for (int kk = 0; kk < 4; kk++) {
                const short8 bfr = *(const short8*)(w1s + swz16(j, (kk << 2) + quad));
                acc = __builtin_amdgcn_mfma_f32_16x16x32_bf16(a[kk], bfr, acc, 0, 0, 0);
            }
#pragma unroll
            for (int r = 0; r < 4; r++) {
                const float temb = silu_f(fmaf(T4[r], wtj[nt], btj[nt]));
                const float h = silu_f(acc[r] + temb + b1j[nt]);
                *(unsigned short*)(hs + swz((quad << 2) + r, j)) = bf1(h);
            }
        }

        short8 a2[4];
#pragma unroll
        for (int kk = 0; kk < 4; kk++) {
            a2[kk] = *(const short8*)(hs + swz16(jl, (kk << 2) + quad));
        }

#pragma unroll
        for (int nt = 0; nt < 8; nt++) {
            f32x4 acc = {0.f, 0.f, 0.f, 0.f};
            const int j = nt * 16 + jl;
#pragma unroll
            for (int kk = 0; kk < 4; kk++) {
                const short8 bfr = *(const short8*)(w2s + swz16(j, (kk << 2) + quad));
                acc = __builtin_amdgcn_mfma_f32_16x16x32_bf16(a2[kk], bfr, acc, 0, 0, 0);
            }
#pragma unroll
            for (int r = 0; r < 4; r++) {
                const float v = acc[r] + b2j[nt];
                const int node = (nt < 4) ? RI[r] : CI[r];
                unsafeAtomicAdd(out + node * DF + (j & 63), v);
            }
        }
    }
}

extern "C" void kernel_launch(void* const* d_in, const int* in_sizes, int n_in,
                              void* d_out, int out_size, void* d_ws, size_t ws_size,
                              hipStream_t stream) {
    const float* x  = (const float*)d_in[0];
    const int*   ei = (const int*)d_in[1];
    const float* t  = (const float*)d_in[2];
    const float* W1 = (const float*)d_in[3];
    const float* b1 = (const float*)d_in[4];
    const float* Wt = (const float*)d_in[5];
    const float* bt = (const float*)d_in[6];
    const float* W2 = (const float*)d_in[7];
    const float* b2 = (const float*)d_in[8];
    float* out = (float*)d_out;

    const size_t eoutB = (size_t)(2 * NEDGE) * 64 * sizeof(unsigned short);  // 204.8 MB
    const size_t need  = eoutB + (size_t)(3 * NNODE + 1 + 1024) * sizeof(int) + 256;

    if (ws_size >= need) {
        char* wsb = (char*)d_ws;
        unsigned short* eout = (unsigned short*)wsb;
        int* counts = (int*)(wsb + eoutB);
        int* offs   = counts + NNODE;          // NNODE+1
        int* bsum   = offs + NNODE + 1;        // 1024
        int* cursor = bsum + 1024;             // NNODE

        // x-bf16 staged in d_out (6.4MB of 12.8MB); dead before gather overwrites out.
        unsigned short* xb = (unsigned short*)d_out;

        const int nsb = (NNODE + 1023) / 1024;  // 49

        hipLaunchKernelGGL(stagex_kernel, dim3((NNODE * DF / 8 + 255) / 256), dim3(256),
                           0, stream, x, xb);
        (void)hipMemsetAsync(counts, 0, (size_t)NNODE * sizeof(int), stream);
        hipLaunchKernelGGL(hist_kernel, dim3((2 * NEDGE + 255) / 256), dim3(256), 0, stream,
                           ei, counts);
        hipLaunchKernelGGL(scan1_kernel, dim3(nsb), dim3(1024), 0, stream,
                           counts, offs, bsum);
        hipLaunchKernelGGL(scan2_kernel, dim3(1), dim3(1024), 0, stream, bsum, nsb);
        hipLaunchKernelGGL(scan3_kernel, dim3(nsb), dim3(1024), 0, stream,
                           offs, bsum, cursor);

        const int ldsMlp = 65536 + WPB * 4096;  // 112KB -> 1 block (12 waves)/CU
        (void)hipFuncSetAttribute((const void*)gnn_mlp_scatter,
                                  hipFuncAttributeMaxDynamicSharedMemorySize, ldsMlp);
        hipLaunchKernelGGL(gnn_mlp_scatter, dim3(256), dim3(BLK), ldsMlp, stream,
                           xb, ei, t, W1, b1, Wt, bt, W2, b2, eout, cursor);

        hipLaunchKernelGGL(gather_kernel, dim3((NNODE + 3) / 4), dim3(256), 0, stream,
                           eout, offs, out);
    } else {
        // fallback: fused atomic version (proven, ~372us)
        const int ldsBytes = 65536 + 4 * 4096;
        (void)hipMemsetAsync(out, 0, (size_t)out_size * sizeof(float), stream);
        (void)hipFuncSetAttribute((const void*)gnn_fused_atomic,
                                  hipFuncAttributeMaxDynamicSharedMemorySize, ldsBytes);
        hipLaunchKernelGGL(gnn_fused_atomic, dim3(512), dim3(256), ldsBytes, stream,
                           x, ei, t, W1, b1, Wt, bt, W2, b2, out);
    }
}

// Round 16
// 229.493 us; speedup vs baseline: 1.2857x; 1.0492x over previous
//
#include <hip/hip_runtime.h>
#include <hip/hip_bf16.h>

#define NEDGE 800000
#define NNODE 50000
#define DF    64
#define HID   128
#define NTILE (NEDGE / 16)
#define BLK   768
#define WPB   12
#define TBINS 2048

using short8 = __attribute__((ext_vector_type(8))) short;
using f32x4  = __attribute__((ext_vector_type(4))) float;
using i32x4  = __attribute__((ext_vector_type(4))) int;

union P8 { unsigned int u[4]; short8 s; };

__device__ __forceinline__ unsigned int pk2(float lo, float hi) {
    union { __hip_bfloat162 p; unsigned int u; } c;
    c.p = __float22bfloat162_rn(float2{lo, hi});
    return c.u;
}

__device__ __forceinline__ unsigned short bf1(float f) {
    union { __hip_bfloat16 b; unsigned short u; } c;
    c.b = __float2bfloat16(f);
    return c.u;
}

__device__ __forceinline__ float bf2f(unsigned short u) {
    union { unsigned int i; float f; } c;
    c.i = ((unsigned int)u) << 16;
    return c.f;
}

// HW transcendentals (R12: __expf/__fdividef are multi-op software without -ffast-math)
__device__ __forceinline__ float exp2_hw(float x) {
    float r; asm("v_exp_f32 %0, %1" : "=v"(r) : "v"(x)); return r;
}
__device__ __forceinline__ float rcp_hw(float x) {
    float r; asm("v_rcp_f32 %0, %1" : "=v"(r) : "v"(x)); return r;
}
__device__ __forceinline__ float silu_f(float v) {
    return v * rcp_hw(1.0f + exp2_hw(v * -1.44269504f));
}

// t-embedding table row load: bin = floor(t*TBINS), row = bf16 temb[bin][0..127]
__device__ __forceinline__ short8 te_load(const unsigned short* __restrict__ ttbl,
                                          float tv, int jl) {
    int tb = (int)(tv * (float)TBINS);
    tb = tb < 0 ? 0 : (tb > TBINS - 1 ? TBINS - 1 : tb);
    return *(const short8*)(ttbl + (size_t)tb * HID + (jl << 3));
}

// XOR-swizzled byte offset inside a row-major [R][128]-bf16 tile (row stride 256B).
__device__ __forceinline__ int swz(int r, int k) {
    return (r << 8) + ((((k >> 3) ^ (r & 7)) << 4) | ((k & 7) << 1));
}
__device__ __forceinline__ int swz16(int r, int slot) {
    return (r << 8) + ((slot ^ (r & 7)) << 4);
}

// ====== prep: x->bf16 stage + temb lookup table + counts zero (one dispatch) ====
__global__ void __launch_bounds__(256)
prep_kernel(const float* __restrict__ x, unsigned short* __restrict__ xb,
            const float* __restrict__ Wt, const float* __restrict__ bt,
            unsigned short* __restrict__ ttbl, int* __restrict__ counts)
{
    const int i = blockIdx.x * 256 + threadIdx.x;
    if (i < NNODE * DF / 8) {
        const f32x4 u = *(const f32x4*)(x + (size_t)i * 8);
        const f32x4 v = *(const f32x4*)(x + (size_t)i * 8 + 4);
        P8 p;
        p.u[0] = pk2(u[0], u[1]); p.u[1] = pk2(u[2], u[3]);
        p.u[2] = pk2(v[0], v[1]); p.u[3] = pk2(v[2], v[3]);
        *(short8*)(xb + (size_t)i * 8) = p.s;
    }
    if (i < TBINS * HID / 8) {
        const int bin = i >> 4;                    // 16 chunks of 8 per 128-col row
        const int j0  = (i & 15) << 3;
        const float tv = (bin + 0.5f) * (1.0f / (float)TBINS);  // bin center
        float e[8];
#pragma unroll
        for (int q = 0; q < 8; q++) e[q] = silu_f(fmaf(tv, Wt[j0 + q], bt[j0 + q]));
        P8 p;
        p.u[0] = pk2(e[0], e[1]); p.u[1] = pk2(e[2], e[3]);
        p.u[2] = pk2(e[4], e[5]); p.u[3] = pk2(e[6], e[7]);
        *(short8*)(ttbl + (size_t)bin * HID + j0) = p.s;
    }
    if (i < NNODE) counts[i] = 0;
}

// ===================== CSR offsets: hist + 3-kernel scan ========================
__global__ void __launch_bounds__(256) hist_kernel(const int* __restrict__ ei,
                                                   int* __restrict__ counts) {
    const int i = blockIdx.x * 256 + threadIdx.x;
    if (i < 2 * NEDGE) atomicAdd(&counts[ei[i]], 1);
}

__global__ void __launch_bounds__(1024) scan1_kernel(const int* __restrict__ counts,
                                                     int* __restrict__ offs,
                                                     int* __restrict__ bsum) {
    __shared__ int buf[1024];
    const int tid = threadIdx.x;
    const int gid = blockIdx.x * 1024 + tid;
    const int v = (gid < NNODE) ? counts[gid] : 0;
    buf[tid] = v;
    __syncthreads();
#pragma unroll
    for (int off = 1; off < 1024; off <<= 1) {
        const int u = (tid >= off) ? buf[tid - off] : 0;
        __syncthreads();
        buf[tid] += u;
        __syncthreads();
    }
    if (gid < NNODE) offs[gid] = buf[tid] - v;     // block-local exclusive
    if (tid == 1023) bsum[blockIdx.x] = buf[1023];
}

__global__ void __launch_bounds__(1024) scan2_kernel(int* __restrict__ bsum, int nb) {
    __shared__ int buf[1024];
    const int tid = threadIdx.x;
    const int v = (tid < nb) ? bsum[tid] : 0;
    buf[tid] = v;
    __syncthreads();
#pragma unroll
    for (int off = 1; off < 1024; off <<= 1) {
        const int u = (tid >= off) ? buf[tid - off] : 0;
        __syncthreads();
        buf[tid] += u;
        __syncthreads();
    }
    if (tid < nb) bsum[tid] = buf[tid] - v;
}

__global__ void __launch_bounds__(1024) scan3_kernel(int* __restrict__ offs,
                                                     const int* __restrict__ bsum,
                                                     int* __restrict__ cursor) {
    const int gid = blockIdx.x * 1024 + threadIdx.x;
    if (gid < NNODE) {
        const int o = offs[gid] + bsum[blockIdx.x];
        offs[gid] = o;
        cursor[gid] = o;
    }
    if (gid == 0) offs[NNODE] = 2 * NEDGE;
}

// ====== Pass 1: edge MLP -> bf16 rows scattered DIRECTLY into CSR slots =========
// 768 threads / 3 waves-per-SIMD; xb pre-staged bf16; temb via L2 table.
__global__ void __launch_bounds__(BLK, 3)
gnn_mlp_scatter(const unsigned short* __restrict__ xb, const int* __restrict__ ei,
                const float* __restrict__ t, const unsigned short* __restrict__ ttbl,
                const float* __restrict__ b1, const float* __restrict__ b2,
                const float* __restrict__ W1, const float* __restrict__ W2,
                unsigned short* __restrict__ eout, int* __restrict__ cursor)
{
    extern __shared__ char lds[];
    char* const w1s = lds;            // 32KB: W1^T bf16, swizzled, PERMUTED rows
    char* const w2s = lds + 32768;    // 32KB: W2^T bf16, swizzled, PERMUTED rows
    const int tid  = threadIdx.x;
    const int wave = tid >> 6;
    const int lane = tid & 63;
    char* const hs = lds + 65536 + (wave << 12);

    // BOTH weights permuted: row rho=((j&7)<<4)+(j>>3) so step nt at lane jl
    // owns actual col jl*8+nt -> 8 ADJACENT cols (16B packed stores, both GEMMs).
    for (int idx = tid; idx < HID * HID; idx += BLK) {
        const int k = idx >> 7, j = idx & 127;
        const int rho = ((j & 7) << 4) + (j >> 3);
        *(unsigned short*)(w1s + swz(rho, k)) = bf1(W1[idx]);
        *(unsigned short*)(w2s + swz(rho, k)) = bf1(W2[idx]);
    }

    const int jl   = lane & 15;
    const int quad = lane >> 4;
    const int k0   = quad << 3;
    float b1j[8], b2j[8];
#pragma unroll
    for (int nt = 0; nt < 8; nt++) {
        const int j = jl * 8 + nt;           // permuted col owned at step nt
        b1j[nt] = b1[j]; b2j[nt] = b2[j];
    }
    __syncthreads();

    const int gwave = blockIdx.x * WPB + wave;
    const int nwave = gridDim.x * WPB;

#define ISSUE_EI(T, RA, CA) { const int e_ = (T) * 16 + jl; RA = ei[e_]; CA = ei[NEDGE + e_]; }
#define ISSUE_X(RA, CA, X_) { \
    const unsigned short* xr_ = xb + (RA) * DF + k0; \
    const unsigned short* xc_ = xb + (CA) * DF + k0; \
    X_[0] = *(const short8*)(xr_);      X_[1] = *(const short8*)(xr_ + 32); \
    X_[2] = *(const short8*)(xc_);      X_[3] = *(const short8*)(xc_ + 32); }
#define ISSUE_EP(T, T4_, RI_, CI_, TE_) { const int er_ = (T) * 16 + (quad << 2); \
    T4_ = *(const f32x4*)(t + er_); \
    RI_ = *(const i32x4*)(ei + er_); \
    CI_ = *(const i32x4*)(ei + NEDGE + er_); \
    TE_[0] = te_load(ttbl, T4_[0], jl); \
    TE_[1] = te_load(ttbl, T4_[1], jl); \
    TE_[2] = te_load(ttbl, T4_[2], jl); \
    TE_[3] = te_load(ttbl, T4_[3], jl); }

    int tile = gwave;
    if (tile < NTILE) {
        int riA, ciA;  ISSUE_EI(tile, riA, ciA);
        short8 X[4];   ISSUE_X(riA, ciA, X);
        f32x4 T4; i32x4 RI, CI; short8 TE[4]; ISSUE_EP(tile, T4, RI, CI, TE);
        int tn  = tile + nwave;
        int tns = (tn < NTILE) ? tn : gwave;
        int riA_n, ciA_n; ISSUE_EI(tns, riA_n, ciA_n);

        while (tile < NTILE) {
            short8 Xn[4]; ISSUE_X(riA_n, ciA_n, Xn);
            f32x4 T4n; i32x4 RIn, CIn; short8 TEn[4]; ISSUE_EP(tns, T4n, RIn, CIn, TEn);
            const int t2  = tn + nwave;
            const int t2s = (t2 < NTILE) ? t2 : gwave;
            int riA_nn, ciA_nn; ISSUE_EI(t2s, riA_nn, ciA_nn);

            // ---- claim CSR slots: 2 fast u32 atomics per edge, broadcast via shfl
            int posS[4], posT[4];
            {
                unsigned int ps[4], pt[4];
#pragma unroll
                for (int r = 0; r < 4; r++) {
                    ps[r] = (jl == 0) ? atomicAdd((unsigned int*)&cursor[RI[r]], 1u) : 0u;
                    pt[r] = (jl == 8) ? atomicAdd((unsigned int*)&cursor[CI[r]], 1u) : 0u;
                }
#pragma unroll
                for (int r = 0; r < 4; r++) {
                    posS[r] = __shfl((int)ps[r], lane & 48);
                    posT[r] = __shfl((int)pt[r], (lane & 48) | 8);
                }
            }

            // ---- GEMM1 (permuted cols): A-frags are the raw bf16 loads
            f32x4 acc1[8];
#pragma unroll
            for (int nt = 0; nt < 8; nt++) {
                f32x4 acc = {0.f, 0.f, 0.f, 0.f};
                const int rho = nt * 16 + jl;
#pragma unroll
                for (int kk = 0; kk < 4; kk++) {
                    const short8 bfr = *(const short8*)(w1s + swz16(rho, (kk << 2) + quad));
                    acc = __builtin_amdgcn_mfma_f32_16x16x32_bf16(X[kk], bfr, acc, 0, 0, 0);
                }
                acc1[nt] = acc;
            }

            // h = silu(acc + temb(table) + b1); 8 adjacent cols -> ONE b128 store/row
#pragma unroll
            for (int r = 0; r < 4; r++) {
                float h[8];
#pragma unroll
                for (int nt = 0; nt < 8; nt++) {
                    h[nt] = silu_f(acc1[nt][r] + bf2f((unsigned short)TE[r][nt]) + b1j[nt]);
                }
                P8 p;
                p.u[0] = pk2(h[0], h[1]);
                p.u[1] = pk2(h[2], h[3]);
                p.u[2] = pk2(h[4], h[5]);
                p.u[3] = pk2(h[6], h[7]);
                *(short8*)(hs + swz16((quad << 2) + r, jl)) = p.s;
            }

            short8 a2[4];
#pragma unroll
            for (int kk = 0; kk < 4; kk++) {
                a2[kk] = *(const short8*)(hs + swz16(jl, (kk << 2) + quad));
            }

            // ---- GEMM2 (permuted cols: lane jl owns cols jl*8 .. jl*8+7)
            f32x4 acc2[8];
#pragma unroll
            for (int nt = 0; nt < 8; nt++) {
                f32x4 acc = {0.f, 0.f, 0.f, 0.f};
                const int rho = nt * 16 + jl;
#pragma unroll
                for (int kk = 0; kk < 4; kk++) {
                    const short8 bfr = *(const short8*)(w2s + swz16(rho, (kk << 2) + quad));
                    acc = __builtin_amdgcn_mfma_f32_16x16x32_bf16(a2[kk], bfr, acc, 0, 0, 0);
                }
                acc2[nt] = acc;
            }

            // ---- scatter rows into CSR slots: 128B contiguous (8 lanes x 16B)
#pragma unroll
            for (int r = 0; r < 4; r++) {
                const int pos = (jl < 8) ? posS[r] : posT[r];
                unsigned short* dst = eout + (size_t)pos * 64 + ((jl & 7) << 3);
                P8 p;
                p.u[0] = pk2(acc2[0][r] + b2j[0], acc2[1][r] + b2j[1]);
                p.u[1] = pk2(acc2[2][r] + b2j[2], acc2[3][r] + b2j[3]);
                p.u[2] = pk2(acc2[4][r] + b2j[4], acc2[5][r] + b2j[5]);
                p.u[3] = pk2(acc2[6][r] + b2j[6], acc2[7][r] + b2j[7]);
                *(short8*)dst = p.s;
            }

            // ---- rotate pipeline state
            tile = tn; tn = t2; tns = t2s;
#pragma unroll
            for (int i = 0; i < 4; i++) { X[i] = Xn[i]; TE[i] = TEn[i]; }
            T4 = T4n; RI = RIn; CI = CIn;
            riA_n = riA_nn; ciA_n = ciA_nn;
        }
    }
#undef ISSUE_EI
#undef ISSUE_X
#undef ISSUE_EP
}

// ======= Pass 2: per-node gather; 16B/lane loads, 8 rows (1KB) per iter =========
__global__ void __launch_bounds__(256)
gather_kernel(const unsigned short* __restrict__ eout, const int* __restrict__ offs,
              float* __restrict__ out)
{
    const int wave = threadIdx.x >> 6;
    const int lane = threadIdx.x & 63;
    const int n = blockIdx.x * 4 + wave;
    if (n >= NNODE) return;
    const int o0 = offs[n], o1 = offs[n + 1];

    const int cg = lane & 7;     // column group (8 bf16 = 16B)
    const int rp = lane >> 3;    // row phase 0..7
    float acc[8] = {0.f, 0.f, 0.f, 0.f, 0.f, 0.f, 0.f, 0.f};
    for (int k = o0 + rp; k < o1; k += 8) {
        const short8 v = *(const short8*)(eout + (size_t)k * 64 + (cg << 3));
#pragma unroll
        for (int j = 0; j < 8; j++) acc[j] += bf2f((unsigned short)v[j]);
    }
#pragma unroll
    for (int j = 0; j < 8; j++) {
        acc[j] += __shfl_xor(acc[j], 8);
        acc[j] += __shfl_xor(acc[j], 16);
        acc[j] += __shfl_xor(acc[j], 32);
    }
    if (rp == 0) {
        float* o = out + (size_t)n * DF + (cg << 3);
        *(f32x4*)(o)     = f32x4{acc[0], acc[1], acc[2], acc[3]};
        *(f32x4*)(o + 4) = f32x4{acc[4], acc[5], acc[6], acc[7]};
    }
}

// ==================== Fallback: fused atomic version (R3, proven 372us) =========
__global__ void __launch_bounds__(256, 2)
gnn_fused_atomic(const float* __restrict__ x, const int* __restrict__ ei,
                 const float* __restrict__ t,
                 const float* __restrict__ W1, const float* __restrict__ b1,
                 const float* __restrict__ Wt, const float* __restrict__ bt,
                 const float* __restrict__ W2, const float* __restrict__ b2,
                 float* __restrict__ out)
{
    extern __shared__ char lds[];
    char* const w1s = lds;
    char* const w2s = lds + 32768;
    const int tid  = threadIdx.x;
    const int wave = tid >> 6;
    const int lane = tid & 63;
    char* const hs = lds + 65536 + (wave << 12);

    for (int idx = tid; idx < HID * HID; idx += 256) {
        const int k = idx >> 7, j = idx & 127;
        const int off = swz(j, k);
        *(unsigned short*)(w1s + off) = bf1(W1[idx]);
        *(unsigned short*)(w2s + off) = bf1(W2[idx]);
    }

    const int jl   = lane & 15;
    const int quad = lane >> 4;
    const int k0   = quad << 3;
    float wtj[8], btj[8], b1j[8], b2j[8];
#pragma unroll
    for (int nt = 0; nt < 8; nt++) {
        const int j = nt * 16 + jl;
        wtj[nt] = Wt[j]; btj[nt] = bt[j]; b1j[nt] = b1[j]; b2j[nt] = b2[j];
    }
    __syncthreads();

    const int gwave = (blockIdx.x << 2) + wave;
    const int nwave = gridDim.x << 2;

    for (int tile = gwave; tile < NTILE; tile += nwave) {
        const int base = tile << 4;
        const int eA = base + jl;
        const int ri = ei[eA];
        const int ci = ei[NEDGE + eA];

        short8 a[4];
        {
            const float* xr_ = x + ri * DF + k0;
            const float* xc_ = x + ci * DF + k0;
            f32x4 u0 = *(const f32x4*)(xr_),      v0 = *(const f32x4*)(xr_ + 4);
            f32x4 u1 = *(const f32x4*)(xr_ + 32), v1 = *(const f32x4*)(xr_ + 36);
            f32x4 u2 = *(const f32x4*)(xc_),      v2 = *(const f32x4*)(xc_ + 4);
            f32x4 u3 = *(const f32x4*)(xc_ + 32), v3 = *(const f32x4*)(xc_ + 36);
            P8 p0, p1, p2, p3;
            p0.u[0]=pk2(u0[0],u0[1]); p0.u[1]=pk2(u0[2],u0[3]); p0.u[2]=pk2(v0[0],v0[1]); p0.u[3]=pk2(v0[2],v0[3]);
            p1.u[0]=pk2(u1[0],u1[1]); p1.u[1]=pk2(u1[2],u1[3]); p1.u[2]=pk2(v1[0],v1[1]); p1.u[3]=pk2(v1[2],v1[3]);
            p2.u[0]=pk2(u2[0],u2[1]); p2.u[1]=pk2(u2[2],u2[3]); p2.u[2]=pk2(v2[0],v2[1]); p2.u[3]=pk2(v2[2],v2[3]);
            p3.u[0]=pk2(u3[0],u3[1]); p3.u[1]=pk2(u3[2],u3[3]); p3.u[2]=pk2(v3[0],v3[1]); p3.u[3]=pk2(v3[2],v3[3]);
            a[0]=p0.s; a[1]=p1.s; a[2]=p2.s; a[3]=p3.s;
        }

        const int er = base + (quad << 2);
        const f32x4 T4 = *(const f32x4*)(t + er);
        const i32x4 RI = *(const i32x4*)(ei + er);
        const i32x4 CI = *(const i32x4*)(ei + NEDGE + er);

#pragma unroll
        for (int nt = 0; nt < 8; nt++) {
            f32x4 acc = {0.f, 0.f, 0.f, 0.f};
            const int j = nt * 16 + jl;
#pragma unroll
            for (int kk = 0; kk < 4; kk++) {
                const short8 bfr = *(const short8*)(w1s + swz16(j, (kk << 2) + quad));
                acc = __builtin_amdgcn_mfma_f32_16x16x32_bf16(a[kk], bfr, acc, 0, 0, 0);
            }
#pragma unroll
            for (int r = 0; r < 4; r++) {
                const float temb = silu_f(fmaf(T4[r], wtj[nt], btj[nt]));
                const float h = silu_f(acc[r] + temb + b1j[nt]);
                *(unsigned short*)(hs + swz((quad << 2) + r, j)) = bf1(h);
            }
        }

        short8 a2[4];
#pragma unroll
        for (int kk = 0; kk < 4; kk++) {
            a2[kk] = *(const short8*)(hs + swz16(jl, (kk << 2) + quad));
        }

#pragma unroll
        for (int nt = 0; nt < 8; nt++) {
            f32x4 acc = {0.f, 0.f, 0.f, 0.f};
            const int j = nt * 16 + jl;
#pragma unroll
            for (int kk = 0; kk < 4; kk++) {
                const short8 bfr = *(const short8*)(w2s + swz16(j, (kk << 2) + quad));
                acc = __builtin_amdgcn_mfma_f32_16x16x32_bf16(a2[kk], bfr, acc, 0, 0, 0);
            }
#pragma unroll
            for (int r = 0; r < 4; r++) {
                const float v = acc[r] + b2j[nt];
                const int node = (nt < 4) ? RI[r] : CI[r];
                unsafeAtomicAdd(out + node * DF + (j & 63), v);
            }
        }
    }
}

extern "C" void kernel_launch(void* const* d_in, const int* in_sizes, int n_in,
                              void* d_out, int out_size, void* d_ws, size_t ws_size,
                              hipStream_t stream) {
    const float* x  = (const float*)d_in[0];
    const int*   ei = (const int*)d_in[1];
    const float* t  = (const float*)d_in[2];
    const float* W1 = (const float*)d_in[3];
    const float* b1 = (const float*)d_in[4];
    const float* Wt = (const float*)d_in[5];
    const float* bt = (const float*)d_in[6];
    const float* W2 = (const float*)d_in[7];
    const float* b2 = (const float*)d_in[8];
    float* out = (float*)d_out;

    const size_t eoutB = (size_t)(2 * NEDGE) * 64 * sizeof(unsigned short);   // 204.8 MB
    const size_t ttblB = (size_t)TBINS * HID * sizeof(unsigned short);        // 512 KB
    const size_t need  = eoutB + ttblB + (size_t)(3 * NNODE + 1 + 1024) * sizeof(int) + 256;

    if (ws_size >= need) {
        char* wsb = (char*)d_ws;
        unsigned short* eout = (unsigned short*)wsb;
        unsigned short* ttbl = (unsigned short*)(wsb + eoutB);   // 16B-aligned
        int* counts = (int*)(wsb + eoutB + ttblB);
        int* offs   = counts + NNODE;          // NNODE+1
        int* bsum   = offs + NNODE + 1;        // 1024
        int* cursor = bsum + 1024;             // NNODE

        // x-bf16 staged in d_out (6.4MB of 12.8MB); dead before gather overwrites out.
        unsigned short* xb = (unsigned short*)d_out;

        const int nsb = (NNODE + 1023) / 1024;  // 49

        hipLaunchKernelGGL(prep_kernel, dim3((NNODE * DF / 8 + 255) / 256), dim3(256),
                           0, stream, x, xb, Wt, bt, ttbl, counts);
        hipLaunchKernelGGL(hist_kernel, dim3((2 * NEDGE + 255) / 256), dim3(256), 0, stream,
                           ei, counts);
        hipLaunchKernelGGL(scan1_kernel, dim3(nsb), dim3(1024), 0, stream,
                           counts, offs, bsum);
        hipLaunchKernelGGL(scan2_kernel, dim3(1), dim3(1024), 0, stream, bsum, nsb);
        hipLaunchKernelGGL(scan3_kernel, dim3(nsb), dim3(1024), 0, stream,
                           offs, bsum, cursor);

        const int ldsMlp = 65536 + WPB * 4096;  // 112KB -> 1 block (12 waves)/CU
        (void)hipFuncSetAttribute((const void*)gnn_mlp_scatter,
                                  hipFuncAttributeMaxDynamicSharedMemorySize, ldsMlp);
        hipLaunchKernelGGL(gnn_mlp_scatter, dim3(256), dim3(BLK), ldsMlp, stream,
                           xb, ei, t, ttbl, b1, b2, W1, W2, eout, cursor);

        hipLaunchKernelGGL(gather_kernel, dim3((NNODE + 3) / 4), dim3(256), 0, stream,
                           eout, offs, out);
    } else {
        // fallback: fused atomic version (proven, ~372us)
        const int ldsBytes = 65536 + 4 * 4096;
        (void)hipMemsetAsync(out, 0, (size_t)out_size * sizeof(float), stream);
        (void)hipFuncSetAttribute((const void*)gnn_fused_atomic,
                                  hipFuncAttributeMaxDynamicSharedMemorySize, ldsBytes);
        hipLaunchKernelGGL(gnn_fused_atomic, dim3(512), dim3(256), ldsBytes, stream,
                           x, ei, t, W1, b1, Wt, bt, W2, b2, out);
    }
}

// Round 17
// 228.053 us; speedup vs baseline: 1.2938x; 1.0063x over previous
//
#include <hip/hip_runtime.h>
#include <hip/hip_bf16.h>

#define NEDGE 800000
#define NNODE 50000
#define DF    64
#define HID   128
#define NTILE (NEDGE / 16)
#define BLK   768
#define WPB   12
#define TBINS 2048

using short8 = __attribute__((ext_vector_type(8))) short;
using f32x4  = __attribute__((ext_vector_type(4))) float;
using i32x4  = __attribute__((ext_vector_type(4))) int;

union P8 { unsigned int u[4]; short8 s; };

__device__ __forceinline__ unsigned int pk2(float lo, float hi) {
    union { __hip_bfloat162 p; unsigned int u; } c;
    c.p = __float22bfloat162_rn(float2{lo, hi});
    return c.u;
}

__device__ __forceinline__ unsigned short bf1(float f) {
    union { __hip_bfloat16 b; unsigned short u; } c;
    c.b = __float2bfloat16(f);
    return c.u;
}

__device__ __forceinline__ float bf2f(unsigned short u) {
    union { unsigned int i; float f; } c;
    c.i = ((unsigned int)u) << 16;
    return c.f;
}

// HW transcendentals (R12: __expf/__fdividef are multi-op software without -ffast-math)
__device__ __forceinline__ float exp2_hw(float x) {
    float r; asm("v_exp_f32 %0, %1" : "=v"(r) : "v"(x)); return r;
}
__device__ __forceinline__ float rcp_hw(float x) {
    float r; asm("v_rcp_f32 %0, %1" : "=v"(r) : "v"(x)); return r;
}
__device__ __forceinline__ float silu_f(float v) {
    return v * rcp_hw(1.0f + exp2_hw(v * -1.44269504f));
}

// t-embedding table row load; t in [0,1) guaranteed (jax.random.uniform) -> no clamp
__device__ __forceinline__ short8 te_load(const unsigned short* __restrict__ ttbl,
                                          float tv, int jl) {
    const int tb = (int)(tv * (float)TBINS);
    return *(const short8*)(ttbl + (size_t)tb * HID + (jl << 3));
}

// XOR-swizzled byte offset inside a row-major [R][128]-bf16 tile (row stride 256B).
__device__ __forceinline__ int swz(int r, int k) {
    return (r << 8) + ((((k >> 3) ^ (r & 7)) << 4) | ((k & 7) << 1));
}
__device__ __forceinline__ int swz16(int r, int slot) {
    return (r << 8) + ((slot ^ (r & 7)) << 4);
}

// ====== prep: x->bf16 stage + temb lookup table + counts zero (one dispatch) ====
__global__ void __launch_bounds__(256)
prep_kernel(const float* __restrict__ x, unsigned short* __restrict__ xb,
            const float* __restrict__ Wt, const float* __restrict__ bt,
            unsigned short* __restrict__ ttbl, int* __restrict__ counts)
{
    const int i = blockIdx.x * 256 + threadIdx.x;
    if (i < NNODE * DF / 8) {
        const f32x4 u = *(const f32x4*)(x + (size_t)i * 8);
        const f32x4 v = *(const f32x4*)(x + (size_t)i * 8 + 4);
        P8 p;
        p.u[0] = pk2(u[0], u[1]); p.u[1] = pk2(u[2], u[3]);
        p.u[2] = pk2(v[0], v[1]); p.u[3] = pk2(v[2], v[3]);
        *(short8*)(xb + (size_t)i * 8) = p.s;
    }
    if (i < TBINS * HID / 8) {
        const int bin = i >> 4;                    // 16 chunks of 8 per 128-col row
        const int j0  = (i & 15) << 3;
        const float tv = (bin + 0.5f) * (1.0f / (float)TBINS);  // bin center
        float e[8];
#pragma unroll
        for (int q = 0; q < 8; q++) e[q] = silu_f(fmaf(tv, Wt[j0 + q], bt[j0 + q]));
        P8 p;
        p.u[0] = pk2(e[0], e[1]); p.u[1] = pk2(e[2], e[3]);
        p.u[2] = pk2(e[4], e[5]); p.u[3] = pk2(e[6], e[7]);
        *(short8*)(ttbl + (size_t)bin * HID + j0) = p.s;
    }
    if (i < NNODE) counts[i] = 0;
}

// ===================== CSR offsets: hist + 3-kernel scan ========================
__global__ void __launch_bounds__(256) hist_kernel(const int* __restrict__ ei,
                                                   int* __restrict__ counts) {
    const int i = blockIdx.x * 256 + threadIdx.x;
    if (i < 2 * NEDGE) atomicAdd(&counts[ei[i]], 1);
}

__global__ void __launch_bounds__(1024) scan1_kernel(const int* __restrict__ counts,
                                                     int* __restrict__ offs,
                                                     int* __restrict__ bsum) {
    __shared__ int buf[1024];
    const int tid = threadIdx.x;
    const int gid = blockIdx.x * 1024 + tid;
    const int v = (gid < NNODE) ? counts[gid] : 0;
    buf[tid] = v;
    __syncthreads();
#pragma unroll
    for (int off = 1; off < 1024; off <<= 1) {
        const int u = (tid >= off) ? buf[tid - off] : 0;
        __syncthreads();
        buf[tid] += u;
        __syncthreads();
    }
    if (gid < NNODE) offs[gid] = buf[tid] - v;     // block-local exclusive
    if (tid == 1023) bsum[blockIdx.x] = buf[1023];
}

__global__ void __launch_bounds__(1024) scan2_kernel(int* __restrict__ bsum, int nb) {
    __shared__ int buf[1024];
    const int tid = threadIdx.x;
    const int v = (tid < nb) ? bsum[tid] : 0;
    buf[tid] = v;
    __syncthreads();
#pragma unroll
    for (int off = 1; off < 1024; off <<= 1) {
        const int u = (tid >= off) ? buf[tid - off] : 0;
        __syncthreads();
        buf[tid] += u;
        __syncthreads();
    }
    if (tid < nb) bsum[tid] = buf[tid] - v;
}

__global__ void __launch_bounds__(1024) scan3_kernel(int* __restrict__ offs,
                                                     const int* __restrict__ bsum,
                                                     int* __restrict__ cursor) {
    const int gid = blockIdx.x * 1024 + threadIdx.x;
    if (gid < NNODE) {
        const int o = offs[gid] + bsum[blockIdx.x];
        offs[gid] = o;
        cursor[gid] = o;
    }
    if (gid == 0) offs[NNODE] = 2 * NEDGE;
}

// ====== Pass 1: edge MLP -> bf16 rows scattered DIRECTLY into CSR slots =========
// 768 threads / 3 waves-per-SIMD; xb pre-staged bf16; temb via L2 table.
__global__ void __launch_bounds__(BLK, 3)
gnn_mlp_scatter(const unsigned short* __restrict__ xb, const int* __restrict__ ei,
                const float* __restrict__ t, const unsigned short* __restrict__ ttbl,
                const float* __restrict__ b1, const float* __restrict__ b2,
                const float* __restrict__ W1, const float* __restrict__ W2,
                unsigned short* __restrict__ eout, int* __restrict__ cursor)
{
    extern __shared__ char lds[];
    char* const w1s = lds;            // 32KB: W1^T bf16, swizzled, PERMUTED rows
    char* const w2s = lds + 32768;    // 32KB: W2^T bf16, swizzled, PERMUTED rows
    const int tid  = threadIdx.x;
    const int wave = tid >> 6;
    const int lane = tid & 63;
    char* const hs = lds + 65536 + (wave << 12);

    // BOTH weights permuted: row rho=((j&7)<<4)+(j>>3) so step nt at lane jl
    // owns actual col jl*8+nt -> 8 ADJACENT cols (16B packed stores, both GEMMs).
    for (int idx = tid; idx < HID * HID; idx += BLK) {
        const int k = idx >> 7, j = idx & 127;
        const int rho = ((j & 7) << 4) + (j >> 3);
        *(unsigned short*)(w1s + swz(rho, k)) = bf1(W1[idx]);
        *(unsigned short*)(w2s + swz(rho, k)) = bf1(W2[idx]);
    }

    const int jl   = lane & 15;
    const int quad = lane >> 4;
    const int k0   = quad << 3;
    float b1j[8], b2j[8];
#pragma unroll
    for (int nt = 0; nt < 8; nt++) {
        const int j = jl * 8 + nt;           // permuted col owned at step nt
        b1j[nt] = b1[j]; b2j[nt] = b2[j];
    }
    __syncthreads();

    const int gwave = blockIdx.x * WPB + wave;
    const int nwave = gridDim.x * WPB;

#define ISSUE_EI(T, RA, CA) { const int e_ = (T) * 16 + jl; RA = ei[e_]; CA = ei[NEDGE + e_]; }
#define ISSUE_X(RA, CA, X_) { \
    const unsigned short* xr_ = xb + (RA) * DF + k0; \
    const unsigned short* xc_ = xb + (CA) * DF + k0; \
    X_[0] = *(const short8*)(xr_);      X_[1] = *(const short8*)(xr_ + 32); \
    X_[2] = *(const short8*)(xc_);      X_[3] = *(const short8*)(xc_ + 32); }
#define ISSUE_EP(T, T4_, RI_, CI_, TE_) { const int er_ = (T) * 16 + (quad << 2); \
    T4_ = *(const f32x4*)(t + er_); \
    RI_ = *(const i32x4*)(ei + er_); \
    CI_ = *(const i32x4*)(ei + NEDGE + er_); \
    TE_[0] = te_load(ttbl, T4_[0], jl); \
    TE_[1] = te_load(ttbl, T4_[1], jl); \
    TE_[2] = te_load(ttbl, T4_[2], jl); \
    TE_[3] = te_load(ttbl, T4_[3], jl); }

    int tile = gwave;
    if (tile < NTILE) {
        int riA, ciA;  ISSUE_EI(tile, riA, ciA);
        short8 X[4];   ISSUE_X(riA, ciA, X);
        f32x4 T4; i32x4 RI, CI; short8 TE[4]; ISSUE_EP(tile, T4, RI, CI, TE);
        int tn  = tile + nwave;
        int tns = (tn < NTILE) ? tn : gwave;
        int riA_n, ciA_n; ISSUE_EI(tns, riA_n, ciA_n);

        while (tile < NTILE) {
            short8 Xn[4]; ISSUE_X(riA_n, ciA_n, Xn);
            f32x4 T4n; i32x4 RIn, CIn; short8 TEn[4]; ISSUE_EP(tns, T4n, RIn, CIn, TEn);
            const int t2  = tn + nwave;
            const int t2s = (t2 < NTILE) ? t2 : gwave;
            int riA_nn, ciA_nn; ISSUE_EI(t2s, riA_nn, ciA_nn);

            // ---- claim CSR slots: 2 fast u32 atomics per edge, broadcast via shfl
            int posS[4], posT[4];
            {
                unsigned int ps[4], pt[4];
#pragma unroll
                for (int r = 0; r < 4; r++) {
                    ps[r] = (jl == 0) ? atomicAdd((unsigned int*)&cursor[RI[r]], 1u) : 0u;
                    pt[r] = (jl == 8) ? atomicAdd((unsigned int*)&cursor[CI[r]], 1u) : 0u;
                }
#pragma unroll
                for (int r = 0; r < 4; r++) {
                    posS[r] = __shfl((int)ps[r], lane & 48);
                    posT[r] = __shfl((int)pt[r], (lane & 48) | 8);
                }
            }

            // ---- GEMM1 (permuted cols): A-frags are the raw bf16 loads
            f32x4 acc1[8];
#pragma unroll
            for (int nt = 0; nt < 8; nt++) {
                f32x4 acc = {0.f, 0.f, 0.f, 0.f};
                const int rho = nt * 16 + jl;
#pragma unroll
                for (int kk = 0; kk < 4; kk++) {
                    const short8 bfr = *(const short8*)(w1s + swz16(rho, (kk << 2) + quad));
                    acc = __builtin_amdgcn_mfma_f32_16x16x32_bf16(X[kk], bfr, acc, 0, 0, 0);
                }
                acc1[nt] = acc;
            }

            // h = silu(acc + temb(table) + b1); 8 adjacent cols -> ONE b128 store/row
#pragma unroll
            for (int r = 0; r < 4; r++) {
                float h[8];
#pragma unroll
                for (int nt = 0; nt < 8; nt++) {
                    h[nt] = silu_f(acc1[nt][r] + bf2f((unsigned short)TE[r][nt]) + b1j[nt]);
                }
                P8 p;
                p.u[0] = pk2(h[0], h[1]);
                p.u[1] = pk2(h[2], h[3]);
                p.u[2] = pk2(h[4], h[5]);
                p.u[3] = pk2(h[6], h[7]);
                *(short8*)(hs + swz16((quad << 2) + r, jl)) = p.s;
            }

            short8 a2[4];
#pragma unroll
            for (int kk = 0; kk < 4; kk++) {
                a2[kk] = *(const short8*)(hs + swz16(jl, (kk << 2) + quad));
            }

            // ---- GEMM2 (permuted cols: lane jl owns cols jl*8 .. jl*8+7)
            f32x4 acc2[8];
#pragma unroll
            for (int nt = 0; nt < 8; nt++) {
                f32x4 acc = {0.f, 0.f, 0.f, 0.f};
                const int rho = nt * 16 + jl;
#pragma unroll
                for (int kk = 0; kk < 4; kk++) {
                    const short8 bfr = *(const short8*)(w2s + swz16(rho, (kk << 2) + quad));
                    acc = __builtin_amdgcn_mfma_f32_16x16x32_bf16(a2[kk], bfr, acc, 0, 0, 0);
                }
                acc2[nt] = acc;
            }

            // ---- scatter rows into CSR slots: 128B contiguous (8 lanes x 16B)
#pragma unroll
            for (int r = 0; r < 4; r++) {
                const int pos = (jl < 8) ? posS[r] : posT[r];
                unsigned short* dst = eout + (size_t)pos * 64 + ((jl & 7) << 3);
                P8 p;
                p.u[0] = pk2(acc2[0][r] + b2j[0], acc2[1][r] + b2j[1]);
                p.u[1] = pk2(acc2[2][r] + b2j[2], acc2[3][r] + b2j[3]);
                p.u[2] = pk2(acc2[4][r] + b2j[4], acc2[5][r] + b2j[5]);
                p.u[3] = pk2(acc2[6][r] + b2j[6], acc2[7][r] + b2j[7]);
                *(short8*)dst = p.s;
            }

            // ---- rotate pipeline state
            tile = tn; tn = t2; tns = t2s;
#pragma unroll
            for (int i = 0; i < 4; i++) { X[i] = Xn[i]; TE[i] = TEn[i]; }
            T4 = T4n; RI = RIn; CI = CIn;
            riA_n = riA_nn; ciA_n = ciA_nn;
        }
    }
#undef ISSUE_EI
#undef ISSUE_X
#undef ISSUE_EP
}

// ======= Pass 2: per-node gather; 32 lanes per node (8 nodes/block) =============
__global__ void __launch_bounds__(256)
gather_kernel(const unsigned short* __restrict__ eout, const int* __restrict__ offs,
              float* __restrict__ out)
{
    const int grp = threadIdx.x >> 5;     // 8 32-lane groups per block
    const int l32 = threadIdx.x & 31;
    const int n = blockIdx.x * 8 + grp;
    if (n >= NNODE) return;
    const int o0 = offs[n], o1 = offs[n + 1];

    const int cg = l32 & 7;     // column group (8 bf16 = 16B)
    const int rp = l32 >> 3;    // row phase 0..3
    float acc[8] = {0.f, 0.f, 0.f, 0.f, 0.f, 0.f, 0.f, 0.f};
    for (int k = o0 + rp; k < o1; k += 4) {
        const short8 v = *(const short8*)(eout + (size_t)k * 64 + (cg << 3));
#pragma unroll
        for (int j = 0; j < 8; j++) acc[j] += bf2f((unsigned short)v[j]);
    }
#pragma unroll
    for (int j = 0; j < 8; j++) {
        acc[j] += __shfl_xor(acc[j], 8);
        acc[j] += __shfl_xor(acc[j], 16);
    }
    if (rp == 0) {
        float* o = out + (size_t)n * DF + (cg << 3);
        *(f32x4*)(o)     = f32x4{acc[0], acc[1], acc[2], acc[3]};
        *(f32x4*)(o + 4) = f32x4{acc[4], acc[5], acc[6], acc[7]};
    }
}

// ==================== Fallback: fused atomic version (R3, proven 372us) =========
__global__ void __launch_bounds__(256, 2)
gnn_fused_atomic(const float* __restrict__ x, const int* __restrict__ ei,
                 const float* __restrict__ t,
                 const float* __restrict__ W1, const float* __restrict__ b1,
                 const float* __restrict__ Wt, const float* __restrict__ bt,
                 const float* __restrict__ W2, const float* __restrict__ b2,
                 float* __restrict__ out)
{
    extern __shared__ char lds[];
    char* const w1s = lds;
    char* const w2s = lds + 32768;
    const int tid  = threadIdx.x;
    const int wave = tid >> 6;
    const int lane = tid & 63;
    char* const hs = lds + 65536 + (wave << 12);

    for (int idx = tid; idx < HID * HID; idx += 256) {
        const int k = idx >> 7, j = idx & 127;
        const int off = swz(j, k);
        *(unsigned short*)(w1s + off) = bf1(W1[idx]);
        *(unsigned short*)(w2s + off) = bf1(W2[idx]);
    }

    const int jl   = lane & 15;
    const int quad = lane >> 4;
    const int k0   = quad << 3;
    float wtj[8], btj[8], b1j[8], b2j[8];
#pragma unroll
    for (int nt = 0; nt < 8; nt++) {
        const int j = nt * 16 + jl;
        wtj[nt] = Wt[j]; btj[nt] = bt[j]; b1j[nt] = b1[j]; b2j[nt] = b2[j];
    }
    __syncthreads();

    const int gwave = (blockIdx.x << 2) + wave;
    const int nwave = gridDim.x << 2;

    for (int tile = gwave; tile < NTILE; tile += nwave) {
        const int base = tile << 4;
        const int eA = base + jl;
        const int ri = ei[eA];
        const int ci = ei[NEDGE + eA];

        short8 a[4];
        {
            const float* xr_ = x + ri * DF + k0;
            const float* xc_ = x + ci * DF + k0;
            f32x4 u0 = *(const f32x4*)(xr_),      v0 = *(const f32x4*)(xr_ + 4);
            f32x4 u1 = *(const f32x4*)(xr_ + 32), v1 = *(const f32x4*)(xr_ + 36);
            f32x4 u2 = *(const f32x4*)(xc_),      v2 = *(const f32x4*)(xc_ + 4);
            f32x4 u3 = *(const f32x4*)(xc_ + 32), v3 = *(const f32x4*)(xc_ + 36);
            P8 p0, p1, p2, p3;
            p0.u[0]=pk2(u0[0],u0[1]); p0.u[1]=pk2(u0[2],u0[3]); p0.u[2]=pk2(v0[0],v0[1]); p0.u[3]=pk2(v0[2],v0[3]);
            p1.u[0]=pk2(u1[0],u1[1]); p1.u[1]=pk2(u1[2],u1[3]); p1.u[2]=pk2(v1[0],v1[1]); p1.u[3]=pk2(v1[2],v1[3]);
            p2.u[0]=pk2(u2[0],u2[1]); p2.u[1]=pk2(u2[2],u2[3]); p2.u[2]=pk2(v2[0],v2[1]); p2.u[3]=pk2(v2[2],v2[3]);
            p3.u[0]=pk2(u3[0],u3[1]); p3.u[1]=pk2(u3[2],u3[3]); p3.u[2]=pk2(v3[0],v3[1]); p3.u[3]=pk2(v3[2],v3[3]);
            a[0]=p0.s; a[1]=p1.s; a[2]=p2.s; a[3]=p3.s;
        }

        const int er = base + (quad << 2);
        const f32x4 T4 = *(const f32x4*)(t + er);
        const i32x4 RI = *(const i32x4*)(ei + er);
        const i32x4 CI = *(const i32x4*)(ei + NEDGE + er);

#pragma unroll
        for (int nt = 0; nt < 8; nt++) {
            f32x4 acc = {0.f, 0.f, 0.f, 0.f};
            const int j = nt * 16 + jl;
#pragma unroll
            for (int kk = 0; kk < 4; kk++) {
                const short8 bfr = *(const short8*)(w1s + swz16(j, (kk << 2) + quad));
                acc = __builtin_amdgcn_mfma_f32_16x16x32_bf16(a[kk], bfr, acc, 0, 0, 0);
            }
#pragma unroll
            for (int r = 0; r < 4; r++) {
                const float temb = silu_f(fmaf(T4[r], wtj[nt], btj[nt]));
                const float h = silu_f(acc[r] + temb + b1j[nt]);
                *(unsigned short*)(hs + swz((quad << 2) + r, j)) = bf1(h);
            }
        }

        short8 a2[4];
#pragma unroll
        for (int kk = 0; kk < 4; kk++) {
            a2[kk] = *(const short8*)(hs + swz16(jl, (kk << 2) + quad));
        }

#pragma unroll
        for (int nt = 0; nt < 8; nt++) {
            f32x4 acc = {0.f, 0.f, 0.f, 0.f};
            const int j = nt * 16 + jl;
#pragma unroll
            for (int kk = 0; kk < 4; kk++) {
                const short8 bfr = *(const short8*)(w2s + swz16(j, (kk << 2) + quad));
                acc = __builtin_amdgcn_mfma_f32_16x16x32_bf16(a2[kk], bfr, acc, 0, 0, 0);
            }
#pragma unroll
            for (int r = 0; r < 4; r++) {
                const float v = acc[r] + b2j[nt];
                const int node = (nt < 4) ? RI[r] : CI[r];
                unsafeAtomicAdd(out + node * DF + (j & 63), v);
            }
        }
    }
}

extern "C" void kernel_launch(void* const* d_in, const int* in_sizes, int n_in,
                              void* d_out, int out_size, void* d_ws, size_t ws_size,
                              hipStream_t stream) {
    const float* x  = (const float*)d_in[0];
    const int*   ei = (const int*)d_in[1];
    const float* t  = (const float*)d_in[2];
    const float* W1 = (const float*)d_in[3];
    const float* b1 = (const float*)d_in[4];
    const float* Wt = (const float*)d_in[5];
    const float* bt = (const float*)d_in[6];
    const float* W2 = (const float*)d_in[7];
    const float* b2 = (const float*)d_in[8];
    float* out = (float*)d_out;

    const size_t eoutB = (size_t)(2 * NEDGE) * 64 * sizeof(unsigned short);   // 204.8 MB
    const size_t ttblB = (size_t)TBINS * HID * sizeof(unsigned short);        // 512 KB
    const size_t need  = eoutB + ttblB + (size_t)(3 * NNODE + 1 + 1024) * sizeof(int) + 256;

    if (ws_size >= need) {
        char* wsb = (char*)d_ws;
        unsigned short* eout = (unsigned short*)wsb;
        unsigned short* ttbl = (unsigned short*)(wsb + eoutB);   // 16B-aligned
        int* counts = (int*)(wsb + eoutB + ttblB);
        int* offs   = counts + NNODE;          // NNODE+1
        int* bsum   = offs + NNODE + 1;        // 1024
        int* cursor = bsum + 1024;             // NNODE

        // x-bf16 staged in d_out (6.4MB of 12.8MB); dead before gather overwrites out.
        unsigned short* xb = (unsigned short*)d_out;

        const int nsb = (NNODE + 1023) / 1024;  // 49

        hipLaunchKernelGGL(prep_kernel, dim3((NNODE * DF / 8 + 255) / 256), dim3(256),
                           0, stream, x, xb, Wt, bt, ttbl, counts);
        hipLaunchKernelGGL(hist_kernel, dim3((2 * NEDGE + 255) / 256), dim3(256), 0, stream,
                           ei, counts);
        hipLaunchKernelGGL(scan1_kernel, dim3(nsb), dim3(1024), 0, stream,
                           counts, offs, bsum);
        hipLaunchKernelGGL(scan2_kernel, dim3(1), dim3(1024), 0, stream, bsum, nsb);
        hipLaunchKernelGGL(scan3_kernel, dim3(nsb), dim3(1024), 0, stream,
                           offs, bsum, cursor);

        const int ldsMlp = 65536 + WPB * 4096;  // 112KB -> 1 block (12 waves)/CU
        (void)hipFuncSetAttribute((const void*)gnn_mlp_scatter,
                                  hipFuncAttributeMaxDynamicSharedMemorySize, ldsMlp);
        hipLaunchKernelGGL(gnn_mlp_scatter, dim3(256), dim3(BLK), ldsMlp, stream,
                           xb, ei, t, ttbl, b1, b2, W1, W2, eout, cursor);

        hipLaunchKernelGGL(gather_kernel, dim3((NNODE + 7) / 8), dim3(256), 0, stream,
                           eout, offs, out);
    } else {
        // fallback: fused atomic version (proven, ~372us)
        const int ldsBytes = 65536 + 4 * 4096;
        (void)hipMemsetAsync(out, 0, (size_t)out_size * sizeof(float), stream);
        (void)hipFuncSetAttribute((const void*)gnn_fused_atomic,
                                  hipFuncAttributeMaxDynamicSharedMemorySize, ldsBytes);
        hipLaunchKernelGGL(gnn_fused_atomic, dim3(512), dim3(256), ldsBytes, stream,
                           x, ei, t, W1, b1, Wt, bt, W2, b2, out);
    }
}